// Round 21
// baseline (186.871 us; speedup 1.0000x reference)
//
#include <hip/hip_runtime.h>
#include <math.h>

namespace {

constexpr int kB  = 2;
constexpr int kN  = 192;
constexpr int kC  = 32;
constexpr int kH  = 64;
constexpr int kNB = 20;
constexpr float kInvSqrtN = 0.07216878364870323f;  // 1/sqrt(192)

typedef __attribute__((ext_vector_type(8))) short bf16x8;
typedef __attribute__((ext_vector_type(4))) float f32x4;

__device__ inline unsigned short bf16r(float x) {   // RNE f32->bf16
    unsigned int u = __float_as_uint(x);
    u = (u + 0x7FFFu + ((u >> 16) & 1u)) >> 16;
    return (unsigned short)u;
}
__device__ inline unsigned int bf16pk(float lo, float hi) {
    return (unsigned int)bf16r(lo) | ((unsigned int)bf16r(hi) << 16);
}

// ---- G rows via MFMA: one wave per (z,h): G_h[b][i] = feat[b][:] @ W2_h^T ----
__device__ inline void g_rows(const float* __restrict__ featz,  // [kN][kC] for this z
                              const float* __restrict__ W2,     // [kH][kC*kC] layer base
                              int z, int h, int lane,
                              unsigned short* __restrict__ Gb)
{
    const int g = lane >> 4, l15 = lane & 15;
    union { bf16x8 v; unsigned short s[8]; } bu0, bu1;
    {
        const float* w0src = W2 + h * (kC * kC) + l15 * kC + 8 * g;
        const float* w1src = W2 + h * (kC * kC) + (16 + l15) * kC + 8 * g;
#pragma unroll
        for (int jj = 0; jj < 8; ++jj) {
            bu0.s[jj] = bf16r(w0src[jj]);
            bu1.s[jj] = bf16r(w1src[jj]);
        }
    }

    const int kb = h >> 3, kk = h & 7;
#pragma unroll
    for (int mt = 0; mt < kN / 16; ++mt) {
        const int b0 = mt * 16;
        const float* asrc = featz + (b0 + l15) * kC + 8 * g;
        union { bf16x8 v; unsigned short s[8]; } au;
#pragma unroll
        for (int jj = 0; jj < 8; ++jj) au.s[jj] = bf16r(asrc[jj]);
        f32x4 acc0 = {0.f, 0.f, 0.f, 0.f};
        f32x4 acc1 = {0.f, 0.f, 0.f, 0.f};
        acc0 = __builtin_amdgcn_mfma_f32_16x16x32_bf16(au.v, bu0.v, acc0, 0, 0, 0);
        acc1 = __builtin_amdgcn_mfma_f32_16x16x32_bf16(au.v, bu1.v, acc1, 0, 0, 0);
#pragma unroll
        for (int r = 0; r < 4; ++r) {
            const int b = b0 + 4 * g + r;
            const size_t base = ((size_t)(z * kN + b) * 8 + kb) * (kC * 8);
            Gb[base + l15 * 8 + kk]        = bf16r(acc0[r]);   // i = l15
            Gb[base + (16 + l15) * 8 + kk] = bf16r(acc1[r]);   // i = 16+l15
        }
    }
}

// ---------------- init: weight packing + acc/counter zeroing + layer-0 G ----------------
__global__ __launch_bounds__(256) void init_kernel(
    const float* __restrict__ W0,
    const float* __restrict__ W1,
    const float* __restrict__ features,   // layer-0 feat
    const float* __restrict__ W2l0,       // layer-0 W2
    unsigned short* __restrict__ wb0,
    unsigned short* __restrict__ wb1,
    unsigned short* __restrict__ Gb,
    float* __restrict__ accf,             // [B*N*C] f32 accumulator
    int* __restrict__ counters)           // [2]
{
    const int tid = threadIdx.x;
    if (blockIdx.x == 0) {
#pragma unroll
        for (int q = 0; q < 2; ++q) {
            const int grp = tid * 2 + q;                 // (l*4+kb)*64 + n
            const int l = grp >> 8, kb = (grp >> 6) & 3, n = grp & 63;
            union { bf16x8 v; unsigned short s[8]; } u;
#pragma unroll
            for (int i = 0; i < 8; ++i) {
                const int k = kb * 8 + i;
                u.s[i] = (k < kNB) ? bf16r(W0[(l * kNB + k) * kH + n]) : (unsigned short)0;
            }
            *reinterpret_cast<bf16x8*>(&wb0[(size_t)grp * 8]) = u.v;
        }
        if (tid < 2) counters[tid] = 0;
        const float4 z4 = make_float4(0.f, 0.f, 0.f, 0.f);
#pragma unroll
        for (int k = 0; k < 12; ++k)                     // 12288 floats = 3072 f4
            *reinterpret_cast<float4*>(&accf[(tid * 12 + k) * 4]) = z4;
    } else if (blockIdx.x == 1) {
#pragma unroll
        for (int q = 0; q < 4; ++q) {
            const int grp = tid * 4 + q;                 // (l*8+kb)*64 + n
            const int l = grp >> 9, kb = (grp >> 6) & 7, n = grp & 63;
            union { bf16x8 v; unsigned short s[8]; } u;
#pragma unroll
            for (int i = 0; i < 8; ++i) {
                const int k = kb * 8 + i;
                u.s[i] = bf16r(W1[(l * kH + k) * kH + n]);
            }
            *reinterpret_cast<bf16x8*>(&wb1[(size_t)grp * 8]) = u.v;
        }
    } else {
        const int wave = tid >> 6, lane = tid & 63;
        const int pair = (blockIdx.x - 2) * 4 + wave;    // 0..127
        const int z = pair >> 6, h = pair & 63;
        g_rows(features + (size_t)z * kN * kC, W2l0, z, h, lane, Gb);
    }
}

// ---------------- g_kernel: G for layer 1 (feat = layer-0 output) ----------------
__global__ __launch_bounds__(256) void g_kernel(
    const float* __restrict__ feat,
    const float* __restrict__ W2,     // layer base
    unsigned short* __restrict__ Gb)
{
    const int wave = threadIdx.x >> 6, lane = threadIdx.x & 63;
    const int pair = blockIdx.x * 4 + wave;              // 0..127
    const int z = pair >> 6, h = pair & 63;
    g_rows(feat + (size_t)z * kN * kC, W2, z, h, lane, Gb);
}

// ---- in-register lane transpose: acc rows (h = 16nt+4g+r, row a=l15) -> B-frag
// window (k = 32ks+8g+i, row a=l15). src lanes (2p)*16+l15 and +16, p=g&1; select nt=2ks+q.
__device__ inline bf16x8 xpose_frag(const unsigned int (&u)[4][2], int ks,
                                    int srcA, int srcB, int q)
{
    union { bf16x8 v; unsigned int w[4]; } r;
    unsigned int lo, hi;
    lo = (unsigned int)__shfl((int)u[2 * ks + 0][0], srcA, 64);
    hi = (unsigned int)__shfl((int)u[2 * ks + 1][0], srcA, 64);
    r.w[0] = q ? hi : lo;
    lo = (unsigned int)__shfl((int)u[2 * ks + 0][1], srcA, 64);
    hi = (unsigned int)__shfl((int)u[2 * ks + 1][1], srcA, 64);
    r.w[1] = q ? hi : lo;
    lo = (unsigned int)__shfl((int)u[2 * ks + 0][0], srcB, 64);
    hi = (unsigned int)__shfl((int)u[2 * ks + 1][0], srcB, 64);
    r.w[2] = q ? hi : lo;
    lo = (unsigned int)__shfl((int)u[2 * ks + 0][1], srcB, 64);
    hi = (unsigned int)__shfl((int)u[2 * ks + 1][1], srcB, 64);
    r.w[3] = q ? hi : lo;
    return r.v;
}

// ---------------- fused kernel: block = (z, bcol). 4 waves x 3 m-tiles. ----------------
// Register-only MLP (r20 body); GEMM-3 results accumulated into f32 acc via HW
// unsafeAtomicAdd; the LAST block (atomic counter) runs the bias/mask epilogue
// (and zeroes acc for the next layer) -> reduce_kernel launches eliminated.
__global__ __launch_bounds__(256, 2) void fused_kernel(
    const float* __restrict__ b0,     // [H] (layer-offset)
    const float* __restrict__ b1,     // [H]
    const float* __restrict__ xyz,    // [B,N,3]
    const unsigned short* __restrict__ wb0,   // layer-offset
    const unsigned short* __restrict__ wb1,   // layer-offset
    const unsigned short* __restrict__ Gb,    // [z*kN+b][2048] frag layout
    float* __restrict__ accf,         // [B*N*C] f32 accumulator (pre-zeroed)
    int* __restrict__ counter,        // this layer's completion counter
    const float* __restrict__ featin, // layer input (for S)
    const float* __restrict__ b2l,    // [C*C] layer-offset
    const float* __restrict__ mask,   // [B,N]
    float* __restrict__ dst,          // layer output
    int zeroAccAfter)                 // 1: re-zero acc for next layer
{
    __shared__ float smem[4 * 64 + 64 + 64];   // redS[4][64], Ssh[64], btsh[64]
    __shared__ int lastFlag;

    const int tid  = threadIdx.x;
    const int wave = tid >> 6, lane = tid & 63;
    const int g = lane >> 4, l15 = lane & 15;
    const int z = blockIdx.x / kN, bcol = blockIdx.x - z * kN;
    const int p = g & 1, q = g >> 1;
    const int srcA = (2 * p) * 16 + l15;
    const int srcB = srcA + 16;

    // --- per-lane weight frags (pre-packed, L2 broadcast) ---
    bf16x8 w0g[4], w1g[2][4];
    f32x4 b0q[4], b1q[4];    // bias vectors: elem r = b{0,1}[nt*16 + 4g + r]
#pragma unroll
    for (int nt = 0; nt < 4; ++nt) {
        w0g[nt] = *reinterpret_cast<const bf16x8*>(&wb0[((size_t)g * kH + nt * 16 + l15) * 8]);
        b0q[nt] = *reinterpret_cast<const f32x4*>(b0 + nt * 16 + 4 * g);
        b1q[nt] = *reinterpret_cast<const f32x4*>(b1 + nt * 16 + 4 * g);
    }
#pragma unroll
    for (int ks = 0; ks < 2; ++ks)
#pragma unroll
        for (int nt = 0; nt < 4; ++nt)
            w1g[ks][nt] = *reinterpret_cast<const bf16x8*>(
                &wb1[((size_t)(ks * 4 + g) * kH + nt * 16 + l15) * 8]);

    // --- G frags from global (4KB row, L2-hot, lane-contiguous) ---
    const unsigned short* gRow = Gb + (size_t)(z * kN + bcol) * 2048;
    bf16x8 bG[2][2];
#pragma unroll
    for (int ks = 0; ks < 2; ++ks)
#pragma unroll
        for (int mi = 0; mi < 2; ++mi)
            bG[ks][mi] = *reinterpret_cast<const bf16x8*>(
                &gRow[((ks * 4 + g) * kC + mi * 16 + l15) * 8]);

    const float bx = xyz[(z * kN + bcol) * 3 + 0];
    const float by = xyz[(z * kN + bcol) * 3 + 1];
    const float bz = xyz[(z * kN + bcol) * 3 + 2];

    // --- hoisted: rb B-frags for all 3 tiles (lane l15 = a-row, elems k = 8g+i) ---
    bf16x8 aRv[3];
#pragma unroll
    for (int t = 0; t < 3; ++t) {
        const int arow = (wave * 3 + t) * 16 + l15;
        const float dx = xyz[(z * kN + arow) * 3 + 0] - bx;
        const float dy = xyz[(z * kN + arow) * 3 + 1] - by;
        const float dz = xyz[(z * kN + arow) * 3 + 2] - bz;
        const float d  = sqrtf(fmaf(dx, dx, fmaf(dy, dy, fmaf(dz, dz, 1e-12f))));
        const float dn = d * (19.0f / 10.0f);   // y_k = clamp(dn - k, -1, 1)
        union { bf16x8 v; unsigned short s[8]; } aU;
#pragma unroll
        for (int i = 0; i < 8; ++i) {
            const float y = fminf(1.f, fmaxf(-1.f, dn - (float)(8 * g + i)));
            aU.s[i] = bf16r(__cosf(1.57079632679f * y));
        }
        aRv[t] = aU.v;   // k>=20 entries hit zero-padded W0 frags
    }

    // --- per-tile loop: all dataflow in registers ---
#pragma unroll
    for (int t = 0; t < 3; ++t) {
        const int m0 = (wave * 3 + t) * 16;

        // GEMM-1 (swapped): acc1[nt][r] = h1pre[a=l15][h=16nt+4g+r]
        f32x4 acc1[4];
#pragma unroll
        for (int nt = 0; nt < 4; ++nt)
            acc1[nt] = __builtin_amdgcn_mfma_f32_16x16x32_bf16(w0g[nt], aRv[t], b0q[nt], 0, 0, 0);

        unsigned int u1[4][2];
#pragma unroll
        for (int nt = 0; nt < 4; ++nt) {
            u1[nt][0] = bf16pk(fmaxf(acc1[nt][0], 0.f), fmaxf(acc1[nt][1], 0.f));
            u1[nt][1] = bf16pk(fmaxf(acc1[nt][2], 0.f), fmaxf(acc1[nt][3], 0.f));
        }

        // GEMM-2 (swapped): acc2[nt][r] = h2pre[a=l15][h=16nt+4g+r]
        f32x4 acc2[4] = {b1q[0], b1q[1], b1q[2], b1q[3]};
#pragma unroll
        for (int ks = 0; ks < 2; ++ks) {
            const bf16x8 hB = xpose_frag(u1, ks, srcA, srcB, q);
#pragma unroll
            for (int nt = 0; nt < 4; ++nt)
                acc2[nt] = __builtin_amdgcn_mfma_f32_16x16x32_bf16(w1g[ks][nt], hB, acc2[nt], 0, 0, 0);
        }

        unsigned int u2[4][2];
#pragma unroll
        for (int nt = 0; nt < 4; ++nt) {
            u2[nt][0] = bf16pk(fmaxf(acc2[nt][0], 0.f), fmaxf(acc2[nt][1], 0.f));
            u2[nt][1] = bf16pk(fmaxf(acc2[nt][2], 0.f), fmaxf(acc2[nt][3], 0.f));
        }

        // GEMM-3 (swapped): D[i][a] -> lane holds out[m0+l15][mi*16+4g+0..3]
        f32x4 accS0 = {0.f, 0.f, 0.f, 0.f}, accS1 = {0.f, 0.f, 0.f, 0.f};
#pragma unroll
        for (int ks = 0; ks < 2; ++ks) {
            const bf16x8 aF = xpose_frag(u2, ks, srcA, srcB, q);
            accS0 = __builtin_amdgcn_mfma_f32_16x16x32_bf16(bG[ks][0], aF, accS0, 0, 0, 0);
            accS1 = __builtin_amdgcn_mfma_f32_16x16x32_bf16(bG[ks][1], aF, accS1, 0, 0, 0);
        }
        // accumulate into f32 acc[z][a][i] via HW global fadd (device scope)
        float* ap = accf + ((size_t)(z * kN) + m0 + l15) * kC + 4 * g;
#pragma unroll
        for (int r = 0; r < 4; ++r) {
            unsafeAtomicAdd(ap + r,      accS0[r]);
            unsafeAtomicAdd(ap + 16 + r, accS1[r]);
        }
    }

    // --- last-block-done epilogue (no spinning) ---
    __threadfence();
    if (tid == 0)
        lastFlag = (atomicAdd(counter, 1) == (int)gridDim.x - 1);
    __syncthreads();
    if (!lastFlag) return;
    __threadfence();

    float* redS = smem;            // [4][64]
    float* Ssh  = smem + 256;      // [64]  S[z][j]
    float* btsh = smem + 320;      // [64]  bt[z][i]

    {   // S[z][j] = sum_b featin[z,b,j]  (4 slices x 64 pairs)
        const int pair = tid & 63, slice = tid >> 6;
        const int zz = pair >> 5, j = pair & 31;
        float s = 0.f;
        for (int b = slice * 48; b < slice * 48 + 48; ++b)
            s += featin[(zz * kN + b) * kC + j];
        redS[slice * 64 + pair] = s;
    }
    __syncthreads();
    if (tid < 64)
        Ssh[tid] = redS[tid] + redS[64 + tid] + redS[128 + tid] + redS[192 + tid];
    __syncthreads();
    if (tid < 64) {
        const int zz = tid >> 5, i = tid & 31;
        float bt = 0.f;
#pragma unroll
        for (int j = 0; j < kC; ++j) bt = fmaf(b2l[i * kC + j], Ssh[zz * kC + j], bt);
        btsh[tid] = bt;
    }
    __syncthreads();

#pragma unroll 4
    for (int k = 0; k < 48; ++k) {
        const int o = tid + 256 * k;             // < 12288
        const int zz = o / (kN * kC);
        const int rem = o - zz * (kN * kC);
        const int a = rem >> 5, i = rem & 31;
        const float v = __hip_atomic_load(&accf[o], __ATOMIC_RELAXED,
                                          __HIP_MEMORY_SCOPE_AGENT);
        dst[o] = (v + btsh[zz * kC + i]) * kInvSqrtN * mask[zz * kN + a];
        if (zeroAccAfter) accf[o] = 0.f;         // visible to next kernel at boundary
    }
}

} // namespace

extern "C" void kernel_launch(void* const* d_in, const int* in_sizes, int n_in,
                              void* d_out, int out_size, void* d_ws, size_t ws_size,
                              hipStream_t stream) {
    const float* features = (const float*)d_in[0];
    const float* xyz      = (const float*)d_in[1];
    const float* mask     = (const float*)d_in[2];
    const float* W0       = (const float*)d_in[3];
    const float* b0       = (const float*)d_in[4];
    const float* W1       = (const float*)d_in[5];
    const float* b1       = (const float*)d_in[6];
    const float* W2       = (const float*)d_in[7];
    const float* b2       = (const float*)d_in[8];
    float* out = (float*)d_out;

    // workspace layout (float offsets):
    //   wb0     :       0 ..   2048   (4096 ushort = 2 layers x 2048)
    //   wb1     :    2048 ..   6144   (8192 ushort = 2 layers x 4096)
    //   Gb      :    6144 .. 399360   (786432 ushort, reused per layer)
    //   accf    :  399360 .. 411648   (12288 f32)
    //   ftmp    :  411648 .. 423936   (12288 f32)
    //   counters:  423936 .. 423938   (int[2])
    float* ws = (float*)d_ws;
    unsigned short* wb0 = (unsigned short*)(ws);
    unsigned short* wb1 = (unsigned short*)(ws + 2048);
    unsigned short* Gb  = (unsigned short*)(ws + 6144);
    float* accf = ws + 399360;
    float* ftmp = ws + 411648;
    int* counters = (int*)(ws + 423936);

    // init: weight packing + acc/counter zero + layer-0 G
    init_kernel<<<34, 256, 0, stream>>>(W0, W1, features, W2, wb0, wb1, Gb,
                                        accf, counters);

    // layer 0: fused (+ last-block epilogue -> ftmp, re-zero acc)
    fused_kernel<<<kB * kN, 256, 0, stream>>>(
        b0, b1, xyz, wb0, wb1, Gb,
        accf, counters + 0, features, b2, mask, ftmp, 1);

    // layer 1: G from ftmp
    g_kernel<<<32, 256, 0, stream>>>(ftmp, W2 + (size_t)kH * kC * kC, Gb);

    // layer 1: fused (+ last-block epilogue -> out)
    fused_kernel<<<kB * kN, 256, 0, stream>>>(
        b0 + kH, b1 + kH, xyz, wb0 + 2048, wb1 + 4096, Gb,
        accf, counters + 1, ftmp, b2 + kC * kC, mask, out, 0);
}

// Round 22
// 45.662 us; speedup vs baseline: 4.0925x; 4.0925x over previous
//
#include <hip/hip_runtime.h>
#include <math.h>

namespace {

constexpr int kB  = 2;
constexpr int kN  = 192;
constexpr int kC  = 32;
constexpr int kH  = 64;
constexpr int kNB = 20;
constexpr int kLayers = 2;
constexpr float kInvSqrtN = 0.07216878364870323f;  // 1/sqrt(192)

typedef __attribute__((ext_vector_type(8))) short bf16x8;
typedef __attribute__((ext_vector_type(4))) float f32x4;

__device__ inline unsigned short bf16r(float x) {   // RNE f32->bf16
    unsigned int u = __float_as_uint(x);
    u = (u + 0x7FFFu + ((u >> 16) & 1u)) >> 16;
    return (unsigned short)u;
}
__device__ inline unsigned int bf16pk(float lo, float hi) {
    return (unsigned int)bf16r(lo) | ((unsigned int)bf16r(hi) << 16);
}
__device__ inline float bf2f(unsigned short v) {
    return __uint_as_float(((unsigned int)v) << 16);
}

// ---- G rows via MFMA: one wave per (z,h): G_h[b][i] = feat[b][:] @ W2_h^T ----
// i spans kC=32 = TWO 16-wide N-tiles.
// Writes Gb[(z*kN+b)*2048 + (h>>3)*256 + i*8 + (h&7)]  (frag layout the fused kernel reads).
__device__ inline void g_rows(const float* __restrict__ featz,  // [kN][kC] for this z
                              const float* __restrict__ W2,     // [kH][kC*kC] layer base
                              int z, int h, int lane,
                              unsigned short* __restrict__ Gb)
{
    const int g = lane >> 4, l15 = lane & 15;
    union { bf16x8 v; unsigned short s[8]; } bu0, bu1;
    {
        const float* w0src = W2 + h * (kC * kC) + l15 * kC + 8 * g;
        const float* w1src = W2 + h * (kC * kC) + (16 + l15) * kC + 8 * g;
#pragma unroll
        for (int jj = 0; jj < 8; ++jj) {
            bu0.s[jj] = bf16r(w0src[jj]);
            bu1.s[jj] = bf16r(w1src[jj]);
        }
    }

    const int kb = h >> 3, kk = h & 7;
#pragma unroll
    for (int mt = 0; mt < kN / 16; ++mt) {
        const int b0 = mt * 16;
        const float* asrc = featz + (b0 + l15) * kC + 8 * g;
        union { bf16x8 v; unsigned short s[8]; } au;
#pragma unroll
        for (int jj = 0; jj < 8; ++jj) au.s[jj] = bf16r(asrc[jj]);
        f32x4 acc0 = {0.f, 0.f, 0.f, 0.f};
        f32x4 acc1 = {0.f, 0.f, 0.f, 0.f};
        acc0 = __builtin_amdgcn_mfma_f32_16x16x32_bf16(au.v, bu0.v, acc0, 0, 0, 0);
        acc1 = __builtin_amdgcn_mfma_f32_16x16x32_bf16(au.v, bu1.v, acc1, 0, 0, 0);
#pragma unroll
        for (int r = 0; r < 4; ++r) {
            const int b = b0 + 4 * g + r;
            const size_t base = ((size_t)(z * kN + b) * 8 + kb) * (kC * 8);
            Gb[base + l15 * 8 + kk]        = bf16r(acc0[r]);   // i = l15
            Gb[base + (16 + l15) * 8 + kk] = bf16r(acc1[r]);   // i = 16+l15
        }
    }
}

// ---------------- init: weight-frag packing (blocks 0,1) + layer-0 G (blocks 2..33) ----------------
__global__ __launch_bounds__(256) void init_kernel(
    const float* __restrict__ W0,
    const float* __restrict__ W1,
    const float* __restrict__ features,   // layer-0 feat
    const float* __restrict__ W2l0,       // layer-0 W2
    unsigned short* __restrict__ wb0,
    unsigned short* __restrict__ wb1,
    unsigned short* __restrict__ Gb)
{
    const int tid = threadIdx.x;
    if (blockIdx.x == 0) {
#pragma unroll
        for (int q = 0; q < 2; ++q) {
            const int grp = tid * 2 + q;                 // (l*4+kb)*64 + n
            const int l = grp >> 8, kb = (grp >> 6) & 3, n = grp & 63;
            union { bf16x8 v; unsigned short s[8]; } u;
#pragma unroll
            for (int i = 0; i < 8; ++i) {
                const int k = kb * 8 + i;
                u.s[i] = (k < kNB) ? bf16r(W0[(l * kNB + k) * kH + n]) : (unsigned short)0;
            }
            *reinterpret_cast<bf16x8*>(&wb0[(size_t)grp * 8]) = u.v;
        }
    } else if (blockIdx.x == 1) {
#pragma unroll
        for (int q = 0; q < 4; ++q) {
            const int grp = tid * 4 + q;                 // (l*8+kb)*64 + n
            const int l = grp >> 9, kb = (grp >> 6) & 7, n = grp & 63;
            union { bf16x8 v; unsigned short s[8]; } u;
#pragma unroll
            for (int i = 0; i < 8; ++i) {
                const int k = kb * 8 + i;
                u.s[i] = bf16r(W1[(l * kH + k) * kH + n]);
            }
            *reinterpret_cast<bf16x8*>(&wb1[(size_t)grp * 8]) = u.v;
        }
    } else {
        const int wave = tid >> 6, lane = tid & 63;
        const int pair = (blockIdx.x - 2) * 4 + wave;    // 0..127
        const int z = pair >> 6, h = pair & 63;
        g_rows(features + (size_t)z * kN * kC, W2l0, z, h, lane, Gb);
    }
}

// ---------------- g_kernel: G for one layer (feat from previous layer's output) ----------------
__global__ __launch_bounds__(256) void g_kernel(
    const float* __restrict__ feat,
    const float* __restrict__ W2,     // layer base
    unsigned short* __restrict__ Gb)
{
    const int wave = threadIdx.x >> 6, lane = threadIdx.x & 63;
    const int pair = blockIdx.x * 4 + wave;              // 0..127
    const int z = pair >> 6, h = pair & 63;
    g_rows(feat + (size_t)z * kN * kC, W2, z, h, lane, Gb);
}

// ---------------- fused kernel: block = (z, bcol). 4 waves x 3 m-tiles. ZERO barriers. ----------------
// h2[a, bcol*64+h] for all 192 a via MFMA MLP (wave-private LDS), then
// GEMM-3 swapped (A=G-frag, B=h2-frag -> D[i][a]) -> coalesced 8B partial stores.
__global__ __launch_bounds__(256, 2) void fused_kernel(
    const float* __restrict__ b0,     // [H]
    const float* __restrict__ b1,     // [H]
    const float* __restrict__ xyz,    // [B,N,3]
    const unsigned short* __restrict__ wb0,   // layer-offset
    const unsigned short* __restrict__ wb1,   // layer-offset
    const unsigned short* __restrict__ Gb,    // [z*kN+b][2048] frag layout
    unsigned short* __restrict__ partialb)    // [z*kN + bcol][kN][kC] bf16
{
    __shared__ __align__(16) unsigned short h1b[4][3][1024];  // per-wave, per-tile 24KB
    __shared__ __align__(16) unsigned short h2b[4][3][1024];  // per-wave, per-tile 24KB

    const int tid  = threadIdx.x;
    const int wave = tid >> 6, lane = tid & 63;
    const int g = lane >> 4, l15 = lane & 15;
    const int z = blockIdx.x / kN, bcol = blockIdx.x - z * kN;

    // --- per-lane weight frags (pre-packed, L2 broadcast) ---
    bf16x8 w0g[4], w1g[2][4];
    float b0v[4], b1v[4];
#pragma unroll
    for (int nt = 0; nt < 4; ++nt) {
        const int n = nt * 16 + l15;
        w0g[nt] = *reinterpret_cast<const bf16x8*>(&wb0[((size_t)g * kH + n) * 8]);
        b0v[nt] = b0[n];
        b1v[nt] = b1[n];
    }
#pragma unroll
    for (int ks = 0; ks < 2; ++ks)
#pragma unroll
        for (int nt = 0; nt < 4; ++nt)
            w1g[ks][nt] = *reinterpret_cast<const bf16x8*>(
                &wb1[((size_t)(ks * 4 + g) * kH + nt * 16 + l15) * 8]);

    // --- G frags from global (4KB row, L2-hot, lane-contiguous) ---
    const unsigned short* gRow = Gb + (size_t)(z * kN + bcol) * 2048;
    bf16x8 bG[2][2];
#pragma unroll
    for (int ks = 0; ks < 2; ++ks)
#pragma unroll
        for (int mi = 0; mi < 2; ++mi)
            bG[ks][mi] = *reinterpret_cast<const bf16x8*>(
                &gRow[((ks * 4 + g) * kC + mi * 16 + l15) * 8]);

    const float bx = xyz[(z * kN + bcol) * 3 + 0];
    const float by = xyz[(z * kN + bcol) * 3 + 1];
    const float bz = xyz[(z * kN + bcol) * 3 + 2];

    // --- pipelined per-tile loop: independent wave-private LDS slices per t ---
#pragma unroll
    for (int t = 0; t < 3; ++t) {
        const int m0 = (wave * 3 + t) * 16;
        unsigned short* h1w = h1b[wave][t];
        unsigned short* h2w = h2b[wave][t];

        // A-frag: rb for edge (arow = m0+l15, bcol), k = 8g+i, in-register
        const int arow = m0 + l15;
        const float dx = xyz[(z * kN + arow) * 3 + 0] - bx;
        const float dy = xyz[(z * kN + arow) * 3 + 1] - by;
        const float dz = xyz[(z * kN + arow) * 3 + 2] - bz;
        const float d  = sqrtf(fmaf(dx, dx, fmaf(dy, dy, fmaf(dz, dz, 1e-12f))));
        const float dn = d * (19.0f / 10.0f);   // y_k = clamp(dn - k, -1, 1)
        union { bf16x8 v; unsigned short s[8]; } aU;
#pragma unroll
        for (int i = 0; i < 8; ++i) {
            const float y = fminf(1.f, fmaxf(-1.f, dn - (float)(8 * g + i)));
            aU.s[i] = bf16r(__cosf(1.57079632679f * y));
        }
        const bf16x8 aR = aU.v;   // k>=20 entries hit zero-padded W0 frags

        // GEMM-1: h1[16 a][64 h] = rb[16 a][K=32] @ W0[32][64]
#pragma unroll
        for (int nt = 0; nt < 4; ++nt) {
            f32x4 acc = {b0v[nt], b0v[nt], b0v[nt], b0v[nt]};
            acc = __builtin_amdgcn_mfma_f32_16x16x32_bf16(aR, w0g[nt], acc, 0, 0, 0);
            const int h = nt * 16 + l15;
            const int kb = h >> 3, kk = h & 7;
#pragma unroll
            for (int r = 0; r < 4; ++r)
                h1w[(kb * 16 + 4 * g + r) * 8 + kk] = bf16r(fmaxf(acc[r], 0.f));
        }
        // wave-private h1 slice; same-wave LDS RAW ordered via lgkmcnt

        // GEMM-2: h2[16 a][64] = h1[16 a][K=64] @ W1[64][64]
        f32x4 acc2[4];
#pragma unroll
        for (int nt = 0; nt < 4; ++nt)
            acc2[nt] = (f32x4){b1v[nt], b1v[nt], b1v[nt], b1v[nt]};
#pragma unroll
        for (int ks = 0; ks < 2; ++ks) {
            const bf16x8 aH = *reinterpret_cast<const bf16x8*>(
                &h1w[((ks * 4 + g) * 16 + l15) * 8]);
#pragma unroll
            for (int nt = 0; nt < 4; ++nt)
                acc2[nt] = __builtin_amdgcn_mfma_f32_16x16x32_bf16(aH, w1g[ks][nt], acc2[nt], 0, 0, 0);
        }
#pragma unroll
        for (int nt = 0; nt < 4; ++nt) {
            const int h = nt * 16 + l15;
            const int kb = h >> 3, kk = h & 7;
#pragma unroll
            for (int r = 0; r < 4; ++r)
                h2w[(kb * 16 + 4 * g + r) * 8 + kk] = bf16r(fmaxf(acc2[nt][r], 0.f));
        }

        // GEMM-3 (swapped): D[i][a] -> lane holds out[m0+l15][mi*16+4g+0..3]
        f32x4 accS0 = {0.f, 0.f, 0.f, 0.f}, accS1 = {0.f, 0.f, 0.f, 0.f};
#pragma unroll
        for (int ks = 0; ks < 2; ++ks) {
            const bf16x8 aF = *reinterpret_cast<const bf16x8*>(
                &h2w[((ks * 4 + g) * 16 + l15) * 8]);
            accS0 = __builtin_amdgcn_mfma_f32_16x16x32_bf16(bG[ks][0], aF, accS0, 0, 0, 0);
            accS1 = __builtin_amdgcn_mfma_f32_16x16x32_bf16(bG[ks][1], aF, accS1, 0, 0, 0);
        }
        unsigned short* pp =
            partialb + ((size_t)(z * kN + bcol) * kN + m0 + l15) * kC + 4 * g;
        uint2 st0, st1;
        st0.x = bf16pk(accS0[0], accS0[1]);
        st0.y = bf16pk(accS0[2], accS0[3]);
        st1.x = bf16pk(accS1[0], accS1[1]);
        st1.y = bf16pk(accS1[2], accS1[3]);
        *reinterpret_cast<uint2*>(pp)      = st0;   // i = 4g .. 4g+3
        *reinterpret_cast<uint2*>(pp + 16) = st1;   // i = 16+4g .. 16+4g+3
    }
}

// ---------------- reduce: block=(z,a). out = (sum_b partial + b2@S) * mask / sqrt(n) ----------------
__global__ __launch_bounds__(256) void reduce_kernel(
    const unsigned short* __restrict__ partialb, // [z*kN + b][kN][kC] bf16
    const float* __restrict__ feat,      // [B*N, C] layer input (for S)
    const float* __restrict__ b2,        // [C*C] (layer-offset)
    const float* __restrict__ mask,      // [B, N]
    float* __restrict__ dst)             // [B, N, C]
{
    __shared__ float redV[16][kC];
    __shared__ float redS[16][kC];
    __shared__ float Ssh[kC], Vsh[kC];

    const int tid = threadIdx.x;
    const int blk = blockIdx.x;              // z*kN + a
    const int z = blk / kN, a = blk - z * kN;
    const int u = tid & 15;                  // i-pair: i = 2u, 2u+1
    const int s = tid >> 4;                  // 16 b-slices of 12

    float a0 = 0.f, a1 = 0.f, s0 = 0.f, s1 = 0.f;
    const unsigned int* pb = reinterpret_cast<const unsigned int*>(
        partialb + ((size_t)(z * kN + s * 12) * kN + a) * kC) + u;
    const float2* fb = reinterpret_cast<const float2*>(
        feat + (size_t)(z * kN + s * 12) * kC) + u;
#pragma unroll 4
    for (int q = 0; q < 12; ++q) {
        const unsigned int w = pb[(size_t)q * kN * (kC / 2)];
        a0 += bf2f((unsigned short)(w & 0xffffu));
        a1 += bf2f((unsigned short)(w >> 16));
        const float2 f2 = fb[q * (kC / 2)];
        s0 += f2.x; s1 += f2.y;
    }
    redV[s][2 * u]     = a0;
    redV[s][2 * u + 1] = a1;
    redS[s][2 * u]     = s0;
    redS[s][2 * u + 1] = s1;
    __syncthreads();

    if (tid < kC) {
        float v = 0.f, sv = 0.f;
#pragma unroll
        for (int q = 0; q < 16; ++q) { v += redV[q][tid]; sv += redS[q][tid]; }
        Vsh[tid] = v;
        Ssh[tid] = sv;
    }
    __syncthreads();

    if (tid < kC) {
        float bt = 0.f;
#pragma unroll
        for (int j = 0; j < kC; ++j) bt = fmaf(b2[tid * kC + j], Ssh[j], bt);
        dst[(size_t)blk * kC + tid] = (Vsh[tid] + bt) * kInvSqrtN * mask[z * kN + a];
    }
}

} // namespace

extern "C" void kernel_launch(void* const* d_in, const int* in_sizes, int n_in,
                              void* d_out, int out_size, void* d_ws, size_t ws_size,
                              hipStream_t stream) {
    const float* features = (const float*)d_in[0];
    const float* xyz      = (const float*)d_in[1];
    const float* mask     = (const float*)d_in[2];
    const float* W0       = (const float*)d_in[3];
    const float* b0       = (const float*)d_in[4];
    const float* W1       = (const float*)d_in[5];
    const float* b1       = (const float*)d_in[6];
    const float* W2       = (const float*)d_in[7];
    const float* b2       = (const float*)d_in[8];
    float* out = (float*)d_out;

    // workspace layout (float offsets):
    //   wb0     :       0 ..    2048   (4096 ushort  = 2 layers x 2048)
    //   wb1     :    2048 ..    6144   (8192 ushort  = 2 layers x 4096)
    //   Gb      :    6144 ..  399360   (786432 ushort, reused per layer)
    //   partialb:  399360 .. 1579008   (2359296 ushort)
    //   ftmp    : 1579008 .. 1591296
    float* ws = (float*)d_ws;
    unsigned short* wb0 = (unsigned short*)(ws);
    unsigned short* wb1 = (unsigned short*)(ws + 2048);
    unsigned short* Gb  = (unsigned short*)(ws + 6144);
    unsigned short* partialb = (unsigned short*)(ws + 399360);
    float* ftmp = ws + 1579008;

    // init: weight packing + layer-0 G
    init_kernel<<<34, 256, 0, stream>>>(W0, W1, features, W2, wb0, wb1, Gb);

    const float* cur = features;
    for (int l = 0; l < kLayers; ++l) {
        float* dst = (l == kLayers - 1) ? out : ftmp;
        if (l > 0)
            g_kernel<<<32, 256, 0, stream>>>(cur, W2 + (size_t)l * kH * kC * kC, Gb);
        fused_kernel<<<kB * kN, 256, 0, stream>>>(
            b0 + (size_t)l * kH, b1 + (size_t)l * kH,
            xyz, wb0 + (size_t)l * 2048, wb1 + (size_t)l * 4096,
            Gb, partialb);
        reduce_kernel<<<kB * kN, 256, 0, stream>>>(
            partialb, cur, b2 + (size_t)l * kC * kC, mask, dst);
        cur = dst;
    }
}